// Round 6
// baseline (710.944 us; speedup 1.0000x reference)
//
#include <hip/hip_runtime.h>
#include <hip/hip_cooperative_groups.h>

namespace cg = cooperative_groups;

#define N_NODES 50000
#define N_EDGES 800000
#define NB_SCAN 196   // ceil(50000 / 256)

typedef unsigned short ushort_t;
typedef __attribute__((ext_vector_type(8))) short  short8v;   // 8 bf16 (4 VGPR) MFMA A/B frag
typedef __attribute__((ext_vector_type(4))) float  float4v;   // MFMA C/D frag
typedef __attribute__((ext_vector_type(4))) unsigned short ushort4v;
typedef __attribute__((ext_vector_type(8))) unsigned short ushort8v;

__device__ __forceinline__ ushort_t f2bf(float f) {
    unsigned u = __float_as_uint(f);
    unsigned r = 0x7fffu + ((u >> 16) & 1u);   // round-to-nearest-even
    return (ushort_t)((u + r) >> 16);
}
__device__ __forceinline__ float bf2f(ushort_t h) {
    return __uint_as_float((unsigned)h << 16);
}

// ---------------- fused CSR build + x->bf16 cast (single cooperative kernel) ----------------
// P0 zero deg + cast x | P1 deg count | P2 chunk sums | P3 scan | P4 rowptr/cursor/inv | P5 scatter

__global__ __launch_bounds__(256) void build_k(const float* __restrict__ x,
                                               ushort_t* __restrict__ xb,
                                               const int* __restrict__ src,
                                               const int* __restrict__ dst,
                                               int* __restrict__ deg,
                                               float* __restrict__ inv,
                                               int* __restrict__ rowptr,
                                               int* __restrict__ cursor,
                                               int* __restrict__ csr,
                                               int* __restrict__ bsum) {
    cg::grid_group grid = cg::this_grid();
    __shared__ int s[256];
    const int t = threadIdx.x, b = blockIdx.x;
    const int nthr = gridDim.x * 256;
    const int gtid = b * 256 + t;

    // P0: zero degree array + cast x (fp32 -> bf16), both grid-strided
    for (int i = gtid; i < N_NODES; i += nthr) deg[i] = 0;
    for (int i = gtid; i < N_NODES * 32; i += nthr) {   // 32 float4 per node row
        float4 v = ((const float4*)x)[i];
        ushort4v h;
        h[0] = f2bf(v.x); h[1] = f2bf(v.y); h[2] = f2bf(v.z); h[3] = f2bf(v.w);
        ((ushort4v*)xb)[i] = h;
    }
    grid.sync();

    // P1: in-degree count
    for (int i = gtid; i < N_EDGES; i += nthr) atomicAdd(deg + dst[i], 1);
    grid.sync();

    // P2: per-256-chunk sums
    if (b < NB_SCAN) {
        int i = b * 256 + t;
        s[t] = (i < N_NODES) ? deg[i] : 0;
        __syncthreads();
#pragma unroll
        for (int off = 128; off > 0; off >>= 1) {
            if (t < off) s[t] += s[t + off];
            __syncthreads();
        }
        if (t == 0) bsum[b] = s[0];
    }
    grid.sync();

    // P3: block 0 scans the chunk sums -> exclusive offsets (in place)
    if (b == 0) {
        int v = (t < NB_SCAN) ? bsum[t] : 0;
        s[t] = v;
        __syncthreads();
#pragma unroll
        for (int off = 1; off < 256; off <<= 1) {
            int u = (t >= off) ? s[t - off] : 0;
            __syncthreads();
            s[t] += u;
            __syncthreads();
        }
        if (t < NB_SCAN) bsum[t] = s[t] - v;
        if (t == 255) rowptr[N_NODES] = s[255];
    }
    grid.sync();

    // P4: rowptr / cursor / inv_deg
    if (b < NB_SCAN) {
        int i = b * 256 + t;
        int d = (i < N_NODES) ? deg[i] : 0;
        s[t] = d;
        __syncthreads();
#pragma unroll
        for (int off = 1; off < 256; off <<= 1) {
            int u = (t >= off) ? s[t - off] : 0;
            __syncthreads();
            s[t] += u;
            __syncthreads();
        }
        if (i < N_NODES) {
            int r = bsum[b] + s[t] - d;
            rowptr[i] = r;
            cursor[i] = r;
            inv[i] = 1.0f / fmaxf((float)d, 1.0f);
        }
    }
    grid.sync();

    // P5: XCD-range-partitioned scatter (csr writes stay local to one XCD's L2)
    {
        const int grp = b & 7;
        const int lo = grp * 6250, hi = lo + 6250;
        const int stride = (gridDim.x >> 3) * 256;
        for (int i = (b >> 3) * 256 + t; i < N_EDGES; i += stride) {
            int d = dst[i];
            if (d >= lo && d < hi) {
                int sv = src[i];
                int pos = atomicAdd(cursor + d, 1);
                csr[pos] = sv;
            }
        }
    }
}

// ---------------- weight packing: fp32 W[128][DOUT] -> bf16 MFMA B-fragment layout ----------------
__global__ __launch_bounds__(256) void pack_all_k(const float* __restrict__ W0n, const float* __restrict__ W0s,
                                                  const float* __restrict__ W1n, const float* __restrict__ W1s,
                                                  const float* __restrict__ W2n, const float* __restrict__ W2s,
                                                  ushort_t* __restrict__ P) {
    int tid = blockIdx.x * 256 + threadIdx.x;
    const float* W; int dout; int base; int r;
    if      (tid < 2048)  { W = W0n; dout = 128; base = 0;     r = tid; }
    else if (tid < 4096)  { W = W0s; dout = 128; base = 16384; r = tid - 2048; }
    else if (tid < 6144)  { W = W1n; dout = 128; base = 32768; r = tid - 4096; }
    else if (tid < 8192)  { W = W1s; dout = 128; base = 49152; r = tid - 6144; }
    else if (tid < 9216)  { W = W2n; dout = 64;  base = 65536; r = tid - 8192; }
    else                  { W = W2s; dout = 64;  base = 73728; r = tid - 9216; }
    int lane = r & 63;
    int ks = (r >> 6) & 3;
    int nt = r >> 8;
    int col = nt * 16 + (lane & 15);
    int k0 = ks * 32 + ((lane >> 4) << 3);
    ushort_t* d = P + (size_t)base + (size_t)r * 8;
    ushort4v lo4, hi4;
#pragma unroll
    for (int j = 0; j < 4; ++j) lo4[j] = f2bf(W[(size_t)(k0 + j) * dout + col]);
#pragma unroll
    for (int j = 0; j < 4; ++j) hi4[j] = f2bf(W[(size_t)(k0 + 4 + j) * dout + col]);
    *(ushort4v*)d = lo4;
    *(ushort4v*)(d + 4) = hi4;
}

// ---------------- gather-mean: m[v] = bf16( inv[v] * sum_j h[csr[j]] )  (128-wide bf16) ----------------
// 16 lanes per node (ushort8 = 16B/lane), 4 nodes per wave, 4-edge unroll -> 16 rows in flight/wave.
__global__ __launch_bounds__(256) void aggm_k(const ushort_t* __restrict__ h,
                                              const int* __restrict__ rowptr,
                                              const int* __restrict__ csr,
                                              const float* __restrict__ inv,
                                              ushort_t* __restrict__ m, int N) {
    int node = (blockIdx.x * 256 + threadIdx.x) >> 4;
    int c = threadIdx.x & 15;
    if (node >= N) return;
    int start = rowptr[node], end = rowptr[node + 1];

    const ushort8v* hp = (const ushort8v*)h;   // row stride 16 (256 B)
    float a0[8] = {}, a1[8] = {}, a2[8] = {}, a3[8] = {};
    int j = start;
    for (; j + 3 < end; j += 4) {
        int u0 = csr[j], u1 = csr[j + 1], u2 = csr[j + 2], u3 = csr[j + 3];
        ushort8v w0 = hp[(size_t)u0 * 16 + c];
        ushort8v w1 = hp[(size_t)u1 * 16 + c];
        ushort8v w2 = hp[(size_t)u2 * 16 + c];
        ushort8v w3 = hp[(size_t)u3 * 16 + c];
#pragma unroll
        for (int k = 0; k < 8; ++k) {
            a0[k] += bf2f(w0[k]); a1[k] += bf2f(w1[k]);
            a2[k] += bf2f(w2[k]); a3[k] += bf2f(w3[k]);
        }
    }
    for (; j < end; ++j) {
        ushort8v w = hp[(size_t)csr[j] * 16 + c];
#pragma unroll
        for (int k = 0; k < 8; ++k) a0[k] += bf2f(w[k]);
    }
    float s = inv[node];
    ushort8v o;
#pragma unroll
    for (int k = 0; k < 8; ++k) o[k] = f2bf(((a0[k] + a1[k]) + (a2[k] + a3[k])) * s);
    ((ushort8v*)m)[(size_t)node * 16 + c] = o;
}

// ---------------- fused dual-A GEMM: Out = bf16(relu(H@Ws + M@Wn + b))  [128 -> 128] ----------------
__global__ __launch_bounds__(256, 2) void fusedgemm_k(const ushort_t* __restrict__ H,
                                                      const ushort_t* __restrict__ M,
                                                      const short8v* __restrict__ Ws,
                                                      const short8v* __restrict__ Wn,
                                                      const float* __restrict__ bias,
                                                      ushort_t* __restrict__ Out, int N) {
    __shared__ ushort_t sm[2][128 * 128];   // 2 x 32 KB
    char* sbH = (char*)sm[0];
    char* sbM = (char*)sm[1];
    const int bm = blockIdx.x * 128;
    const int t = threadIdx.x;
    const int w = t >> 6, l = t & 63;

    {
        const ushort8v* Hp = (const ushort8v*)H;
        const ushort8v* Mp = (const ushort8v*)M;
        ushort8v zeroV = {0, 0, 0, 0, 0, 0, 0, 0};
#pragma unroll
        for (int it = 0; it < 8; ++it) {
            int r = it * 16 + (t >> 4);
            int row = bm + r;
            int byte = (r * 256 + (t & 15) * 16) ^ ((r & 7) << 4);
            ushort8v vh = zeroV, vm = zeroV;
            if (row < N) {
                vh = Hp[(size_t)row * 16 + (t & 15)];
                vm = Mp[(size_t)row * 16 + (t & 15)];
            }
            *(ushort8v*)(sbH + byte) = vh;
            *(ushort8v*)(sbM + byte) = vm;
        }
    }
    __syncthreads();

    float bv[8];
#pragma unroll
    for (int nt = 0; nt < 8; ++nt) bv[nt] = bias[nt * 16 + (l & 15)];

    float4v acc[2][8] = {};
#pragma unroll
    for (int ks = 0; ks < 4; ++ks) {
        int r0 = w * 32 + (l & 15);
        int r1 = r0 + 16;
        int b0 = (r0 * 256 + ks * 64 + (l >> 4) * 16) ^ ((r0 & 7) << 4);
        int b1 = (r1 * 256 + ks * 64 + (l >> 4) * 16) ^ ((r1 & 7) << 4);
        short8v ah0 = *(const short8v*)(sbH + b0);
        short8v ah1 = *(const short8v*)(sbH + b1);
        short8v am0 = *(const short8v*)(sbM + b0);
        short8v am1 = *(const short8v*)(sbM + b1);
#pragma unroll
        for (int nt = 0; nt < 8; ++nt) {
            short8v bs = Ws[(nt * 4 + ks) * 64 + l];
            short8v bn = Wn[(nt * 4 + ks) * 64 + l];
            acc[0][nt] = __builtin_amdgcn_mfma_f32_16x16x32_bf16(ah0, bs, acc[0][nt], 0, 0, 0);
            acc[0][nt] = __builtin_amdgcn_mfma_f32_16x16x32_bf16(am0, bn, acc[0][nt], 0, 0, 0);
            acc[1][nt] = __builtin_amdgcn_mfma_f32_16x16x32_bf16(ah1, bs, acc[1][nt], 0, 0, 0);
            acc[1][nt] = __builtin_amdgcn_mfma_f32_16x16x32_bf16(am1, bn, acc[1][nt], 0, 0, 0);
        }
    }

    // C/D layout: col = lane&15, row = (lane>>4)*4 + i  [verified m89]
#pragma unroll
    for (int mi = 0; mi < 2; ++mi) {
#pragma unroll
        for (int i = 0; i < 4; ++i) {
            int row = bm + w * 32 + mi * 16 + (l >> 4) * 4 + i;
            if (row < N) {
#pragma unroll
                for (int nt = 0; nt < 8; ++nt) {
                    int col = nt * 16 + (l & 15);
                    Out[(size_t)row * 128 + col] = f2bf(fmaxf(acc[mi][nt][i] + bv[nt], 0.f));
                }
            }
        }
    }
}

// ---------------- layer-2 dual GEMM: S(fp32,->out) = H@Wself + b ; Z(bf16) = H@Wneigh  [128 -> 64] ----------------
__global__ __launch_bounds__(256, 2) void dual64_k(const ushort_t* __restrict__ A,
                                                   const short8v* __restrict__ Wn,
                                                   const short8v* __restrict__ Ws,
                                                   const float* __restrict__ bias,
                                                   ushort_t* __restrict__ Z,
                                                   float* __restrict__ S, int N) {
    constexpr int NT = 4;
    __shared__ ushort_t Asm[128 * 128];
    char* sb = (char*)Asm;
    const int bm = blockIdx.x * 128;
    const int t = threadIdx.x;
    const int w = t >> 6, l = t & 63;

    {
        const ushort8v* Ap = (const ushort8v*)A;
        ushort8v zeroV = {0, 0, 0, 0, 0, 0, 0, 0};
#pragma unroll
        for (int it = 0; it < 8; ++it) {
            int r = it * 16 + (t >> 4);
            int row = bm + r;
            ushort8v v = zeroV;
            if (row < N) v = Ap[(size_t)row * 16 + (t & 15)];
            int byte = (r * 256 + (t & 15) * 16) ^ ((r & 7) << 4);
            *(ushort8v*)(sb + byte) = v;
        }
    }
    __syncthreads();

    float bv[NT];
#pragma unroll
    for (int nt = 0; nt < NT; ++nt) bv[nt] = bias[nt * 16 + (l & 15)];

    float4v accS[2][NT] = {}, accN[2][NT] = {};
#pragma unroll
    for (int ks = 0; ks < 4; ++ks) {
        int r0 = w * 32 + (l & 15);
        int b0 = (r0 * 256 + ks * 64 + (l >> 4) * 16) ^ ((r0 & 7) << 4);
        short8v a0 = *(const short8v*)(sb + b0);
        int r1 = r0 + 16;
        int b1 = (r1 * 256 + ks * 64 + (l >> 4) * 16) ^ ((r1 & 7) << 4);
        short8v a1 = *(const short8v*)(sb + b1);
#pragma unroll
        for (int nt = 0; nt < NT; ++nt) {
            short8v bs = Ws[(nt * 4 + ks) * 64 + l];
            short8v bn = Wn[(nt * 4 + ks) * 64 + l];
            accS[0][nt] = __builtin_amdgcn_mfma_f32_16x16x32_bf16(a0, bs, accS[0][nt], 0, 0, 0);
            accS[1][nt] = __builtin_amdgcn_mfma_f32_16x16x32_bf16(a1, bs, accS[1][nt], 0, 0, 0);
            accN[0][nt] = __builtin_amdgcn_mfma_f32_16x16x32_bf16(a0, bn, accN[0][nt], 0, 0, 0);
            accN[1][nt] = __builtin_amdgcn_mfma_f32_16x16x32_bf16(a1, bn, accN[1][nt], 0, 0, 0);
        }
    }

#pragma unroll
    for (int mi = 0; mi < 2; ++mi) {
#pragma unroll
        for (int i = 0; i < 4; ++i) {
            int row = bm + w * 32 + mi * 16 + (l >> 4) * 4 + i;
            if (row < N) {
#pragma unroll
                for (int nt = 0; nt < NT; ++nt) {
                    int col = nt * 16 + (l & 15);
                    S[(size_t)row * 64 + col] = accS[mi][nt][i] + bv[nt];
                    Z[(size_t)row * 64 + col] = f2bf(accN[mi][nt][i]);
                }
            }
        }
    }
}

// ---------------- layer-2 aggregation: out(fp32,=S) += inv * sum z[nbr]  (64-wide) ----------------
// 8 lanes per node (ushort8 = 16B/lane), 8 nodes per wave, 4-edge unroll -> 32 rows in flight/wave.
__global__ __launch_bounds__(256) void agg64_k(const ushort_t* __restrict__ z,
                                               const int* __restrict__ rowptr,
                                               const int* __restrict__ csr,
                                               const float* __restrict__ inv,
                                               float* __restrict__ out, int N) {
    int node = (blockIdx.x * 256 + threadIdx.x) >> 3;
    int c = threadIdx.x & 7;
    if (node >= N) return;
    int start = rowptr[node], end = rowptr[node + 1];

    const ushort8v* zp = (const ushort8v*)z;   // row stride 8 (128 B)
    float a0[8] = {}, a1[8] = {}, a2[8] = {}, a3[8] = {};
    int j = start;
    for (; j + 3 < end; j += 4) {
        int u0 = csr[j], u1 = csr[j + 1], u2 = csr[j + 2], u3 = csr[j + 3];
        ushort8v w0 = zp[(size_t)u0 * 8 + c];
        ushort8v w1 = zp[(size_t)u1 * 8 + c];
        ushort8v w2 = zp[(size_t)u2 * 8 + c];
        ushort8v w3 = zp[(size_t)u3 * 8 + c];
#pragma unroll
        for (int k = 0; k < 8; ++k) {
            a0[k] += bf2f(w0[k]); a1[k] += bf2f(w1[k]);
            a2[k] += bf2f(w2[k]); a3[k] += bf2f(w3[k]);
        }
    }
    for (; j < end; ++j) {
        ushort8v w = zp[(size_t)csr[j] * 8 + c];
#pragma unroll
        for (int k = 0; k < 8; ++k) a0[k] += bf2f(w[k]);
    }
    float s = inv[node];
    float* op = out + (size_t)node * 64 + c * 8;
    float4 o0 = *(float4*)op;
    float4 o1 = *(float4*)(op + 4);
    o0.x += ((a0[0] + a1[0]) + (a2[0] + a3[0])) * s;
    o0.y += ((a0[1] + a1[1]) + (a2[1] + a3[1])) * s;
    o0.z += ((a0[2] + a1[2]) + (a2[2] + a3[2])) * s;
    o0.w += ((a0[3] + a1[3]) + (a2[3] + a3[3])) * s;
    o1.x += ((a0[4] + a1[4]) + (a2[4] + a3[4])) * s;
    o1.y += ((a0[5] + a1[5]) + (a2[5] + a3[5])) * s;
    o1.z += ((a0[6] + a1[6]) + (a2[6] + a3[6])) * s;
    o1.w += ((a0[7] + a1[7]) + (a2[7] + a3[7])) * s;
    *(float4*)op = o0;
    *(float4*)(op + 4) = o1;
}

// ---------------- launch ----------------

extern "C" void kernel_launch(void* const* d_in, const int* in_sizes, int n_in,
                              void* d_out, int out_size, void* d_ws, size_t ws_size,
                              hipStream_t stream) {
    const float* x       = (const float*)d_in[0];
    const int*   src     = (const int*)d_in[1];
    const int*   dst     = (const int*)d_in[2];
    const float* Wself0  = (const float*)d_in[3];
    const float* Wneigh0 = (const float*)d_in[4];
    const float* b0      = (const float*)d_in[5];
    const float* Wself1  = (const float*)d_in[6];
    const float* Wneigh1 = (const float*)d_in[7];
    const float* b1      = (const float*)d_in[8];
    const float* Wself2  = (const float*)d_in[9];
    const float* Wneigh2 = (const float*)d_in[10];
    const float* b2      = (const float*)d_in[11];
    float* out = (float*)d_out;

    char* ws = (char*)d_ws;
    size_t off = 0;
    auto alloc = [&](size_t bytes) -> void* {
        void* p = ws + off;
        off += (bytes + 255) & ~(size_t)255;
        return p;
    };
    int*      deg    = (int*)alloc((size_t)N_NODES * 4);
    float*    inv    = (float*)alloc((size_t)N_NODES * 4);
    int*      rowptr = (int*)alloc((size_t)(N_NODES + 1) * 4);
    int*      cursor = (int*)alloc((size_t)N_NODES * 4);
    int*      csr    = (int*)alloc((size_t)N_EDGES * 4);
    int*      bsum   = (int*)alloc((size_t)NB_SCAN * 4);
    ushort_t* packW  = (ushort_t*)alloc((size_t)81920 * 2);
    ushort_t* xb     = (ushort_t*)alloc((size_t)N_NODES * 128 * 2);
    ushort_t* mbuf   = (ushort_t*)alloc((size_t)N_NODES * 128 * 2);
    ushort_t* h1     = (ushort_t*)alloc((size_t)N_NODES * 128 * 2);
    ushort_t* h2     = (ushort_t*)alloc((size_t)N_NODES * 128 * 2);
    ushort_t* z64    = (ushort_t*)alloc((size_t)N_NODES * 64 * 2);

    dim3 b256(256);
    const int gemmBlocks  = (N_NODES + 127) / 128;        // 391
    const int aggmBlocks  = (N_NODES * 16 + 255) / 256;   // 3125
    const int agg64Blocks = (N_NODES * 8 + 255) / 256;    // 1563

    // ---- fused CSR build + cast (cooperative: 1024 blocks x 256 = 4 blocks/CU) ----
    {
        void* args[] = {(void*)&x, (void*)&xb, (void*)&src, (void*)&dst,
                        (void*)&deg, (void*)&inv, (void*)&rowptr, (void*)&cursor,
                        (void*)&csr, (void*)&bsum};
        hipLaunchCooperativeKernel(reinterpret_cast<const void*>(build_k),
                                   dim3(1024), b256, args, 0, stream);
    }

    // ---- weight packing ----
    pack_all_k<<<40, b256, 0, stream>>>(Wneigh0, Wself0, Wneigh1, Wself1, Wneigh2, Wself2, packW);
    const short8v* pN0 = (const short8v*)(packW);
    const short8v* pS0 = (const short8v*)(packW + 16384);
    const short8v* pN1 = (const short8v*)(packW + 32768);
    const short8v* pS1 = (const short8v*)(packW + 49152);
    const short8v* pN2 = (const short8v*)(packW + 65536);
    const short8v* pS2 = (const short8v*)(packW + 73728);

    // layer 0 (agg-first): m = mean(xb[nbr]); h1 = relu(xb@Ws0 + m@Wn0 + b0)
    aggm_k<<<aggmBlocks, b256, 0, stream>>>(xb, rowptr, csr, inv, mbuf, N_NODES);
    fusedgemm_k<<<gemmBlocks, b256, 0, stream>>>(xb, mbuf, pS0, pN0, b0, h1, N_NODES);

    // layer 1 (agg-first): m = mean(h1[nbr]); h2 = relu(h1@Ws1 + m@Wn1 + b1)
    aggm_k<<<aggmBlocks, b256, 0, stream>>>(h1, rowptr, csr, inv, mbuf, N_NODES);
    fusedgemm_k<<<gemmBlocks, b256, 0, stream>>>(h1, mbuf, pS1, pN1, b1, h2, N_NODES);

    // layer 2 (gemm-first): out = h2@Ws2 + b2 ; z = bf16(h2@Wn2) ; out += inv*segsum(z)
    dual64_k<<<gemmBlocks, b256, 0, stream>>>(h2, pN2, pS2, b2, z64, out, N_NODES);
    agg64_k<<<agg64Blocks, b256, 0, stream>>>(z64, rowptr, csr, inv, out, N_NODES);
}

// Round 7
// 218.375 us; speedup vs baseline: 3.2556x; 3.2556x over previous
//
#include <hip/hip_runtime.h>

#define N_NODES 50000
#define N_EDGES 800000
#define NB_SCAN 196   // ceil(50000 / 256)

typedef unsigned short ushort_t;
typedef __attribute__((ext_vector_type(8))) short  short8v;   // 8 bf16 (4 VGPR) MFMA A/B frag
typedef __attribute__((ext_vector_type(4))) float  float4v;   // MFMA C/D frag
typedef __attribute__((ext_vector_type(4))) unsigned short ushort4v;
typedef __attribute__((ext_vector_type(8))) unsigned short ushort8v;

__device__ __forceinline__ ushort_t f2bf(float f) {
    unsigned u = __float_as_uint(f);
    unsigned r = 0x7fffu + ((u >> 16) & 1u);   // round-to-nearest-even
    return (ushort_t)((u + r) >> 16);
}
__device__ __forceinline__ float bf2f(ushort_t h) {
    return __uint_as_float((unsigned)h << 16);
}

// ---------------- cast x -> bf16, and zero deg (independent work, one dispatch) ----------------
__global__ __launch_bounds__(256) void cast_zero_k(const float* __restrict__ x,
                                                   ushort_t* __restrict__ xb,
                                                   int* __restrict__ deg, int n4) {
    int i = blockIdx.x * 256 + threadIdx.x;
    if (i < n4) {
        float4 v = ((const float4*)x)[i];
        ushort4v h;
        h[0] = f2bf(v.x); h[1] = f2bf(v.y); h[2] = f2bf(v.z); h[3] = f2bf(v.w);
        ((ushort4v*)xb)[i] = h;
    }
    if (i < N_NODES) deg[i] = 0;
}

// ---------------- CSR build (separate kernels — grid.sync on MI355X costs ~100µs, never fuse) ----------------

__global__ void deg_count_k(const int* __restrict__ dst, int* __restrict__ deg, int nE) {
    int i = blockIdx.x * blockDim.x + threadIdx.x;
    if (i < nE) atomicAdd(deg + dst[i], 1);
}

__global__ __launch_bounds__(256) void block_sum_k(const int* __restrict__ deg,
                                                   int* __restrict__ bsum, int n) {
    __shared__ int s[256];
    int t = threadIdx.x, b = blockIdx.x;
    int i = b * 256 + t;
    s[t] = (i < n) ? deg[i] : 0;
    __syncthreads();
#pragma unroll
    for (int off = 128; off > 0; off >>= 1) {
        if (t < off) s[t] += s[t + off];
        __syncthreads();
    }
    if (t == 0) bsum[b] = s[0];
}

__global__ __launch_bounds__(256) void scan_bsum_k(const int* __restrict__ bsum,
                                                   int* __restrict__ boff,
                                                   int* __restrict__ rowptr_last, int nb) {
    __shared__ int s[256];
    int t = threadIdx.x;
    int v = (t < nb) ? bsum[t] : 0;
    s[t] = v;
    __syncthreads();
#pragma unroll
    for (int off = 1; off < 256; off <<= 1) {
        int u = (t >= off) ? s[t - off] : 0;
        __syncthreads();
        s[t] += u;
        __syncthreads();
    }
    if (t < nb) boff[t] = s[t] - v;
    if (t == 255) *rowptr_last = s[255];
}

__global__ __launch_bounds__(256) void write_rowptr_k(const int* __restrict__ deg,
                                                      const int* __restrict__ boff,
                                                      int* __restrict__ rowptr,
                                                      int* __restrict__ cursor,
                                                      float* __restrict__ inv, int n) {
    __shared__ int s[256];
    int t = threadIdx.x, b = blockIdx.x;
    int i = b * 256 + t;
    int d = (i < n) ? deg[i] : 0;
    s[t] = d;
    __syncthreads();
#pragma unroll
    for (int off = 1; off < 256; off <<= 1) {
        int u = (t >= off) ? s[t - off] : 0;
        __syncthreads();
        s[t] += u;
        __syncthreads();
    }
    if (i < n) {
        int r = boff[b] + s[t] - d;
        rowptr[i] = r;
        cursor[i] = r;
        inv[i] = 1.0f / fmaxf((float)d, 1.0f);
    }
}

// XCD-range-partitioned scatter (keeps csr writes local to one XCD's L2)
__global__ __launch_bounds__(256) void scatter_k(const int* __restrict__ src,
                                                 const int* __restrict__ dst,
                                                 int* __restrict__ cursor,
                                                 int* __restrict__ csr, int nE) {
    const int grp = blockIdx.x & 7;
    const int lo = grp * 6250, hi = lo + 6250;
    const int stride = (gridDim.x >> 3) * 256;
    for (int i = (blockIdx.x >> 3) * 256 + threadIdx.x; i < nE; i += stride) {
        int d = dst[i];
        if (d >= lo && d < hi) {
            int s = src[i];
            int pos = atomicAdd(cursor + d, 1);
            csr[pos] = s;
        }
    }
}

// ---------------- weight packing: fp32 W[128][DOUT] -> bf16 MFMA B-fragment layout ----------------
__global__ __launch_bounds__(256) void pack_all_k(const float* __restrict__ W0n, const float* __restrict__ W0s,
                                                  const float* __restrict__ W1n, const float* __restrict__ W1s,
                                                  const float* __restrict__ W2n, const float* __restrict__ W2s,
                                                  ushort_t* __restrict__ P) {
    int tid = blockIdx.x * 256 + threadIdx.x;
    const float* W; int dout; int base; int r;
    if      (tid < 2048)  { W = W0n; dout = 128; base = 0;     r = tid; }
    else if (tid < 4096)  { W = W0s; dout = 128; base = 16384; r = tid - 2048; }
    else if (tid < 6144)  { W = W1n; dout = 128; base = 32768; r = tid - 4096; }
    else if (tid < 8192)  { W = W1s; dout = 128; base = 49152; r = tid - 6144; }
    else if (tid < 9216)  { W = W2n; dout = 64;  base = 65536; r = tid - 8192; }
    else                  { W = W2s; dout = 64;  base = 73728; r = tid - 9216; }
    int lane = r & 63;
    int ks = (r >> 6) & 3;
    int nt = r >> 8;
    int col = nt * 16 + (lane & 15);
    int k0 = ks * 32 + ((lane >> 4) << 3);
    ushort_t* d = P + (size_t)base + (size_t)r * 8;
    ushort4v lo4, hi4;
#pragma unroll
    for (int j = 0; j < 4; ++j) lo4[j] = f2bf(W[(size_t)(k0 + j) * dout + col]);
#pragma unroll
    for (int j = 0; j < 4; ++j) hi4[j] = f2bf(W[(size_t)(k0 + 4 + j) * dout + col]);
    *(ushort4v*)d = lo4;
    *(ushort4v*)(d + 4) = hi4;
}

// ---------------- gather-mean: m[v] = bf16( inv[v] * sum_j h[csr[j]] )  (128-wide bf16) ----------------
// 16 lanes per node (ushort8 = 16B/lane), 4 nodes per wave, 4-edge unroll -> 16 rows in flight/wave.
__global__ __launch_bounds__(256) void aggm_k(const ushort_t* __restrict__ h,
                                              const int* __restrict__ rowptr,
                                              const int* __restrict__ csr,
                                              const float* __restrict__ inv,
                                              ushort_t* __restrict__ m, int N) {
    int node = (blockIdx.x * 256 + threadIdx.x) >> 4;
    int c = threadIdx.x & 15;
    if (node >= N) return;
    int start = rowptr[node], end = rowptr[node + 1];

    const ushort8v* hp = (const ushort8v*)h;   // row stride 16 (256 B)
    float a0[8] = {}, a1[8] = {}, a2[8] = {}, a3[8] = {};
    int j = start;
    for (; j + 3 < end; j += 4) {
        int u0 = csr[j], u1 = csr[j + 1], u2 = csr[j + 2], u3 = csr[j + 3];
        ushort8v w0 = hp[(size_t)u0 * 16 + c];
        ushort8v w1 = hp[(size_t)u1 * 16 + c];
        ushort8v w2 = hp[(size_t)u2 * 16 + c];
        ushort8v w3 = hp[(size_t)u3 * 16 + c];
#pragma unroll
        for (int k = 0; k < 8; ++k) {
            a0[k] += bf2f(w0[k]); a1[k] += bf2f(w1[k]);
            a2[k] += bf2f(w2[k]); a3[k] += bf2f(w3[k]);
        }
    }
    for (; j < end; ++j) {
        ushort8v w = hp[(size_t)csr[j] * 16 + c];
#pragma unroll
        for (int k = 0; k < 8; ++k) a0[k] += bf2f(w[k]);
    }
    float s = inv[node];
    ushort8v o;
#pragma unroll
    for (int k = 0; k < 8; ++k) o[k] = f2bf(((a0[k] + a1[k]) + (a2[k] + a3[k])) * s);
    ((ushort8v*)m)[(size_t)node * 16 + c] = o;
}

// ---------------- fused dual-A GEMM: Out = bf16(relu(H@Ws + M@Wn + b))  [128 -> 128] ----------------
__global__ __launch_bounds__(256, 2) void fusedgemm_k(const ushort_t* __restrict__ H,
                                                      const ushort_t* __restrict__ M,
                                                      const short8v* __restrict__ Ws,
                                                      const short8v* __restrict__ Wn,
                                                      const float* __restrict__ bias,
                                                      ushort_t* __restrict__ Out, int N) {
    __shared__ ushort_t sm[2][128 * 128];   // 2 x 32 KB
    char* sbH = (char*)sm[0];
    char* sbM = (char*)sm[1];
    const int bm = blockIdx.x * 128;
    const int t = threadIdx.x;
    const int w = t >> 6, l = t & 63;

    {
        const ushort8v* Hp = (const ushort8v*)H;
        const ushort8v* Mp = (const ushort8v*)M;
        ushort8v zeroV = {0, 0, 0, 0, 0, 0, 0, 0};
#pragma unroll
        for (int it = 0; it < 8; ++it) {
            int r = it * 16 + (t >> 4);
            int row = bm + r;
            int byte = (r * 256 + (t & 15) * 16) ^ ((r & 7) << 4);
            ushort8v vh = zeroV, vm = zeroV;
            if (row < N) {
                vh = Hp[(size_t)row * 16 + (t & 15)];
                vm = Mp[(size_t)row * 16 + (t & 15)];
            }
            *(ushort8v*)(sbH + byte) = vh;
            *(ushort8v*)(sbM + byte) = vm;
        }
    }
    __syncthreads();

    float bv[8];
#pragma unroll
    for (int nt = 0; nt < 8; ++nt) bv[nt] = bias[nt * 16 + (l & 15)];

    float4v acc[2][8] = {};
#pragma unroll
    for (int ks = 0; ks < 4; ++ks) {
        int r0 = w * 32 + (l & 15);
        int r1 = r0 + 16;
        int b0 = (r0 * 256 + ks * 64 + (l >> 4) * 16) ^ ((r0 & 7) << 4);
        int b1 = (r1 * 256 + ks * 64 + (l >> 4) * 16) ^ ((r1 & 7) << 4);
        short8v ah0 = *(const short8v*)(sbH + b0);
        short8v ah1 = *(const short8v*)(sbH + b1);
        short8v am0 = *(const short8v*)(sbM + b0);
        short8v am1 = *(const short8v*)(sbM + b1);
#pragma unroll
        for (int nt = 0; nt < 8; ++nt) {
            short8v bs = Ws[(nt * 4 + ks) * 64 + l];
            short8v bn = Wn[(nt * 4 + ks) * 64 + l];
            acc[0][nt] = __builtin_amdgcn_mfma_f32_16x16x32_bf16(ah0, bs, acc[0][nt], 0, 0, 0);
            acc[0][nt] = __builtin_amdgcn_mfma_f32_16x16x32_bf16(am0, bn, acc[0][nt], 0, 0, 0);
            acc[1][nt] = __builtin_amdgcn_mfma_f32_16x16x32_bf16(ah1, bs, acc[1][nt], 0, 0, 0);
            acc[1][nt] = __builtin_amdgcn_mfma_f32_16x16x32_bf16(am1, bn, acc[1][nt], 0, 0, 0);
        }
    }

    // C/D layout: col = lane&15, row = (lane>>4)*4 + i  [verified m89]
#pragma unroll
    for (int mi = 0; mi < 2; ++mi) {
#pragma unroll
        for (int i = 0; i < 4; ++i) {
            int row = bm + w * 32 + mi * 16 + (l >> 4) * 4 + i;
            if (row < N) {
#pragma unroll
                for (int nt = 0; nt < 8; ++nt) {
                    int col = nt * 16 + (l & 15);
                    Out[(size_t)row * 128 + col] = f2bf(fmaxf(acc[mi][nt][i] + bv[nt], 0.f));
                }
            }
        }
    }
}

// ---------------- layer-2 dual GEMM: S(fp32,->out) = H@Wself + b ; Z(bf16) = H@Wneigh  [128 -> 64] ----------------
__global__ __launch_bounds__(256, 2) void dual64_k(const ushort_t* __restrict__ A,
                                                   const short8v* __restrict__ Wn,
                                                   const short8v* __restrict__ Ws,
                                                   const float* __restrict__ bias,
                                                   ushort_t* __restrict__ Z,
                                                   float* __restrict__ S, int N) {
    constexpr int NT = 4;
    __shared__ ushort_t Asm[128 * 128];
    char* sb = (char*)Asm;
    const int bm = blockIdx.x * 128;
    const int t = threadIdx.x;
    const int w = t >> 6, l = t & 63;

    {
        const ushort8v* Ap = (const ushort8v*)A;
        ushort8v zeroV = {0, 0, 0, 0, 0, 0, 0, 0};
#pragma unroll
        for (int it = 0; it < 8; ++it) {
            int r = it * 16 + (t >> 4);
            int row = bm + r;
            ushort8v v = zeroV;
            if (row < N) v = Ap[(size_t)row * 16 + (t & 15)];
            int byte = (r * 256 + (t & 15) * 16) ^ ((r & 7) << 4);
            *(ushort8v*)(sb + byte) = v;
        }
    }
    __syncthreads();

    float bv[NT];
#pragma unroll
    for (int nt = 0; nt < NT; ++nt) bv[nt] = bias[nt * 16 + (l & 15)];

    float4v accS[2][NT] = {}, accN[2][NT] = {};
#pragma unroll
    for (int ks = 0; ks < 4; ++ks) {
        int r0 = w * 32 + (l & 15);
        int b0 = (r0 * 256 + ks * 64 + (l >> 4) * 16) ^ ((r0 & 7) << 4);
        short8v a0 = *(const short8v*)(sb + b0);
        int r1 = r0 + 16;
        int b1 = (r1 * 256 + ks * 64 + (l >> 4) * 16) ^ ((r1 & 7) << 4);
        short8v a1 = *(const short8v*)(sb + b1);
#pragma unroll
        for (int nt = 0; nt < NT; ++nt) {
            short8v bs = Ws[(nt * 4 + ks) * 64 + l];
            short8v bn = Wn[(nt * 4 + ks) * 64 + l];
            accS[0][nt] = __builtin_amdgcn_mfma_f32_16x16x32_bf16(a0, bs, accS[0][nt], 0, 0, 0);
            accS[1][nt] = __builtin_amdgcn_mfma_f32_16x16x32_bf16(a1, bs, accS[1][nt], 0, 0, 0);
            accN[0][nt] = __builtin_amdgcn_mfma_f32_16x16x32_bf16(a0, bn, accN[0][nt], 0, 0, 0);
            accN[1][nt] = __builtin_amdgcn_mfma_f32_16x16x32_bf16(a1, bn, accN[1][nt], 0, 0, 0);
        }
    }

#pragma unroll
    for (int mi = 0; mi < 2; ++mi) {
#pragma unroll
        for (int i = 0; i < 4; ++i) {
            int row = bm + w * 32 + mi * 16 + (l >> 4) * 4 + i;
            if (row < N) {
#pragma unroll
                for (int nt = 0; nt < NT; ++nt) {
                    int col = nt * 16 + (l & 15);
                    S[(size_t)row * 64 + col] = accS[mi][nt][i] + bv[nt];
                    Z[(size_t)row * 64 + col] = f2bf(accN[mi][nt][i]);
                }
            }
        }
    }
}

// ---------------- layer-2 aggregation: out(fp32,=S) += inv * sum z[nbr]  (64-wide) ----------------
// 8 lanes per node (ushort8 = 16B/lane), 8 nodes per wave, 4-edge unroll -> 32 rows in flight/wave.
__global__ __launch_bounds__(256) void agg64_k(const ushort_t* __restrict__ z,
                                               const int* __restrict__ rowptr,
                                               const int* __restrict__ csr,
                                               const float* __restrict__ inv,
                                               float* __restrict__ out, int N) {
    int node = (blockIdx.x * 256 + threadIdx.x) >> 3;
    int c = threadIdx.x & 7;
    if (node >= N) return;
    int start = rowptr[node], end = rowptr[node + 1];

    const ushort8v* zp = (const ushort8v*)z;   // row stride 8 (128 B)
    float a0[8] = {}, a1[8] = {}, a2[8] = {}, a3[8] = {};
    int j = start;
    for (; j + 3 < end; j += 4) {
        int u0 = csr[j], u1 = csr[j + 1], u2 = csr[j + 2], u3 = csr[j + 3];
        ushort8v w0 = zp[(size_t)u0 * 8 + c];
        ushort8v w1 = zp[(size_t)u1 * 8 + c];
        ushort8v w2 = zp[(size_t)u2 * 8 + c];
        ushort8v w3 = zp[(size_t)u3 * 8 + c];
#pragma unroll
        for (int k = 0; k < 8; ++k) {
            a0[k] += bf2f(w0[k]); a1[k] += bf2f(w1[k]);
            a2[k] += bf2f(w2[k]); a3[k] += bf2f(w3[k]);
        }
    }
    for (; j < end; ++j) {
        ushort8v w = zp[(size_t)csr[j] * 8 + c];
#pragma unroll
        for (int k = 0; k < 8; ++k) a0[k] += bf2f(w[k]);
    }
    float s = inv[node];
    float* op = out + (size_t)node * 64 + c * 8;
    float4 o0 = *(float4*)op;
    float4 o1 = *(float4*)(op + 4);
    o0.x += ((a0[0] + a1[0]) + (a2[0] + a3[0])) * s;
    o0.y += ((a0[1] + a1[1]) + (a2[1] + a3[1])) * s;
    o0.z += ((a0[2] + a1[2]) + (a2[2] + a3[2])) * s;
    o0.w += ((a0[3] + a1[3]) + (a2[3] + a3[3])) * s;
    o1.x += ((a0[4] + a1[4]) + (a2[4] + a3[4])) * s;
    o1.y += ((a0[5] + a1[5]) + (a2[5] + a3[5])) * s;
    o1.z += ((a0[6] + a1[6]) + (a2[6] + a3[6])) * s;
    o1.w += ((a0[7] + a1[7]) + (a2[7] + a3[7])) * s;
    *(float4*)op = o0;
    *(float4*)(op + 4) = o1;
}

// ---------------- launch ----------------

extern "C" void kernel_launch(void* const* d_in, const int* in_sizes, int n_in,
                              void* d_out, int out_size, void* d_ws, size_t ws_size,
                              hipStream_t stream) {
    const float* x       = (const float*)d_in[0];
    const int*   src     = (const int*)d_in[1];
    const int*   dst     = (const int*)d_in[2];
    const float* Wself0  = (const float*)d_in[3];
    const float* Wneigh0 = (const float*)d_in[4];
    const float* b0      = (const float*)d_in[5];
    const float* Wself1  = (const float*)d_in[6];
    const float* Wneigh1 = (const float*)d_in[7];
    const float* b1      = (const float*)d_in[8];
    const float* Wself2  = (const float*)d_in[9];
    const float* Wneigh2 = (const float*)d_in[10];
    const float* b2      = (const float*)d_in[11];
    float* out = (float*)d_out;

    char* ws = (char*)d_ws;
    size_t off = 0;
    auto alloc = [&](size_t bytes) -> void* {
        void* p = ws + off;
        off += (bytes + 255) & ~(size_t)255;
        return p;
    };
    int*      deg    = (int*)alloc((size_t)N_NODES * 4);
    float*    inv    = (float*)alloc((size_t)N_NODES * 4);
    int*      rowptr = (int*)alloc((size_t)(N_NODES + 1) * 4);
    int*      cursor = (int*)alloc((size_t)N_NODES * 4);
    int*      csr    = (int*)alloc((size_t)N_EDGES * 4);
    int*      bsum   = (int*)alloc((size_t)NB_SCAN * 4);
    int*      boff   = (int*)alloc((size_t)NB_SCAN * 4);
    ushort_t* packW  = (ushort_t*)alloc((size_t)81920 * 2);
    ushort_t* xb     = (ushort_t*)alloc((size_t)N_NODES * 128 * 2);
    ushort_t* mbuf   = (ushort_t*)alloc((size_t)N_NODES * 128 * 2);
    ushort_t* h1     = (ushort_t*)alloc((size_t)N_NODES * 128 * 2);
    ushort_t* h2     = (ushort_t*)alloc((size_t)N_NODES * 128 * 2);
    ushort_t* z64    = (ushort_t*)alloc((size_t)N_NODES * 64 * 2);

    dim3 b256(256);
    const int edgeBlocks  = (N_EDGES + 255) / 256;
    const int gemmBlocks  = (N_NODES + 127) / 128;        // 391
    const int aggmBlocks  = (N_NODES * 16 + 255) / 256;   // 3125
    const int agg64Blocks = (N_NODES * 8 + 255) / 256;    // 1563
    const int castBlocks  = (N_NODES * 32 + 255) / 256;   // 6250

    // ---- CSR build (separate small dispatches; cheaper than coop grid.sync on this chip) ----
    cast_zero_k<<<castBlocks, b256, 0, stream>>>(x, xb, deg, N_NODES * 32);
    deg_count_k<<<edgeBlocks, b256, 0, stream>>>(dst, deg, N_EDGES);
    block_sum_k<<<NB_SCAN, b256, 0, stream>>>(deg, bsum, N_NODES);
    scan_bsum_k<<<1, b256, 0, stream>>>(bsum, boff, rowptr + N_NODES, NB_SCAN);
    write_rowptr_k<<<NB_SCAN, b256, 0, stream>>>(deg, boff, rowptr, cursor, inv, N_NODES);
    scatter_k<<<1024, b256, 0, stream>>>(src, dst, cursor, csr, N_EDGES);

    // ---- weight packing ----
    pack_all_k<<<40, b256, 0, stream>>>(Wneigh0, Wself0, Wneigh1, Wself1, Wneigh2, Wself2, packW);
    const short8v* pN0 = (const short8v*)(packW);
    const short8v* pS0 = (const short8v*)(packW + 16384);
    const short8v* pN1 = (const short8v*)(packW + 32768);
    const short8v* pS1 = (const short8v*)(packW + 49152);
    const short8v* pN2 = (const short8v*)(packW + 65536);
    const short8v* pS2 = (const short8v*)(packW + 73728);

    // layer 0 (agg-first): m = mean(xb[nbr]); h1 = relu(xb@Ws0 + m@Wn0 + b0)
    aggm_k<<<aggmBlocks, b256, 0, stream>>>(xb, rowptr, csr, inv, mbuf, N_NODES);
    fusedgemm_k<<<gemmBlocks, b256, 0, stream>>>(xb, mbuf, pS0, pN0, b0, h1, N_NODES);

    // layer 1 (agg-first): m = mean(h1[nbr]); h2 = relu(h1@Ws1 + m@Wn1 + b1)
    aggm_k<<<aggmBlocks, b256, 0, stream>>>(h1, rowptr, csr, inv, mbuf, N_NODES);
    fusedgemm_k<<<gemmBlocks, b256, 0, stream>>>(h1, mbuf, pS1, pN1, b1, h2, N_NODES);

    // layer 2 (gemm-first): out = h2@Ws2 + b2 ; z = bf16(h2@Wn2) ; out += inv*segsum(z)
    dual64_k<<<gemmBlocks, b256, 0, stream>>>(h2, pN2, pS2, b2, z64, out, N_NODES);
    agg64_k<<<agg64Blocks, b256, 0, stream>>>(z64, rowptr, csr, inv, out, N_NODES);
}